// Round 13
// baseline (228.649 us; speedup 1.0000x reference)
//
#include <hip/hip_runtime.h>
#include <hip/hip_fp16.h>
#include <hip/hip_cooperative_groups.h>

namespace cg = cooperative_groups;

#define GRIDN 256
#define NVOX (GRIDN * GRIDN * GRIDN)   // 64 MiB fp32
#define NYT  32                        // y-tiles of 8 rows
#define NBKT (GRIDN * NYT)             // 8192 buckets: key = z*32 + (y>>3)
#define BCAP 256                       // bucket capacity (lambda ~61)
#define CSTR 32                        // cnt stride in ints (128 B/counter)

#define TYF   8
#define WROWS 12                       // y0-2 .. y0+9
#define ZS    8
#define NBLK  512                      // cooperative grid: 2 blocks/CU (4/CU fits)
#define NTHR  256

typedef float floatx4 __attribute__((ext_vector_type(4)));

// LDS-only barrier: don't drain vmcnt (record prefetch + output stores stay in flight).
#define BAR_LDS()                                              \
    do {                                                       \
        asm volatile("s_waitcnt lgkmcnt(0)" ::: "memory");     \
        __builtin_amdgcn_sched_barrier(0);                     \
        __builtin_amdgcn_s_barrier();                          \
        __builtin_amdgcn_sched_barrier(0);                     \
    } while (0)

// ---------------------------------------------------------------------------
// Single cooperative kernel: phase0 zero cnt -> sync -> phase1 bin ->
// sync -> phase2 fused 5x5x5 box conv (3-buffer, 1 barrier/slice).
// cnt/rec cross phases within one dispatch across XCDs -> all accesses to
// them are agent-scope atomics (per-XCD L2s are not coherent; no launch
// boundary to invalidate them).
// ---------------------------------------------------------------------------
__global__ __launch_bounds__(NTHR, 4)
void k_all(const float* __restrict__ feats, const int* __restrict__ coords,
           int* __restrict__ cnt, unsigned int* __restrict__ rec,
           float* __restrict__ out, int n) {
    cg::grid_group grid = cg::this_grid();
    const int tid  = threadIdx.x;
    const int bid  = blockIdx.x;
    const int gtid = bid * NTHR + tid;

    // ---- Phase 0: zero bucket counters (1 MiB) ----
    for (int i = gtid; i < NBKT * CSTR; i += NBLK * NTHR)
        __hip_atomic_store(&cnt[i], 0, __ATOMIC_RELAXED, __HIP_MEMORY_SCOPE_AGENT);
    grid.sync();

    // ---- Phase 1: bin points. record = {x:8, y:8, f16:16} ----
    for (int i = gtid; i < n; i += NBLK * NTHR) {
        int d = coords[3 * i + 0];
        int h = coords[3 * i + 1];
        int w = coords[3 * i + 2];
        int key  = d * NYT + (h >> 3);
        int slot = __hip_atomic_fetch_add(&cnt[key * CSTR], 1,
                                          __ATOMIC_RELAXED, __HIP_MEMORY_SCOPE_AGENT);
        if (slot < BCAP) {
            unsigned int r = (unsigned int)w | ((unsigned int)h << 8)
                           | ((unsigned int)__half_as_ushort(__float2half(feats[i])) << 16);
            __hip_atomic_store(&rec[(size_t)key * BCAP + slot], r,
                               __ATOMIC_RELAXED, __HIP_MEMORY_SCOPE_AGENT);
        }
    }
    __threadfence();
    grid.sync();

    // ---- Phase 2: fused conv. Block handles 2 adjacent y-tiles of one z-seg ----
    __shared__ float Xp[3][WROWS][256];
    __shared__ int   cm[ZS + 4][3];
    __shared__ int   cb_[ZS + 4][3];

    // XCD-chunked swizzle over 512 blocks; pair = 2 adjacent y-tiles.
    const int swz   = (bid & 7) * 64 + (bid >> 3);
    const int zseg  = swz >> 4;          // 0..31
    const int ypair = swz & 15;          // 0..15
    const int z0    = zseg * ZS;

    const int xq  = (tid & 63) * 4;      // float4 col within the row
    const int yy2 = (tid >> 6) * 2;      // 2 output rows per thread

    for (int sub = 0; sub < 2; ++sub) {
        const int y0  = (ypair * 2 + sub) * TYF;
        const int yt0 = y0 >> 3;

        // Zero all 3 buffers; load 36 bucket counts. (Prev tile's reads ended in a BAR.)
        for (int idx = tid; idx < 3 * WROWS * 64; idx += NTHR)
            ((float4*)Xp)[idx] = make_float4(0.f, 0.f, 0.f, 0.f);
        if (tid < 3 * (ZS + 4)) {
            int k = tid / 3, t = tid - 3 * k;
            int zi = z0 - 2 + k;
            int yt = yt0 - 1 + t;
            int m = 0, b = -1;
            if ((unsigned)zi < (unsigned)GRIDN && (unsigned)yt < (unsigned)NYT) {
                b = zi * NYT + yt;
                m = min(__hip_atomic_load(&cnt[b * CSTR],
                                          __ATOMIC_RELAXED, __HIP_MEMORY_SCOPE_AGENT), BCAP);
            }
            cm[k][t]  = m;
            cb_[k][t] = b;
        }
        BAR_LDS();

        auto load_rec = [&](int k, int j) -> unsigned int {
            int m0 = cm[k][0], m1 = cm[k][1];
            int b, s;
            if (j < m0)           { b = cb_[k][0]; s = j; }
            else if (j < m0 + m1) { b = cb_[k][1]; s = j - m0; }
            else                  { b = cb_[k][2]; s = j - m0 - m1; }
            return __hip_atomic_load(&rec[(size_t)b * BCAP + s],
                                     __ATOMIC_RELAXED, __HIP_MEMORY_SCOPE_AGENT);
        };

        // Prefetch slice 0 records.
        unsigned int p0 = 0, p1 = 0, p2 = 0;
        {
            int M = cm[0][0] + cm[0][1] + cm[0][2];
            if (tid < M)       p0 = load_rec(0, tid);
            if (tid + 256 < M) p1 = load_rec(0, tid + 256);
            if (tid + 512 < M) p2 = load_rec(0, tid + 512);
        }

        float4 a0 = {0,0,0,0}, a1 = {0,0,0,0}, a2 = {0,0,0,0}, a3 = {0,0,0,0}, a4 = {0,0,0,0};
        float4 b0 = {0,0,0,0}, b1 = {0,0,0,0}, b2 = {0,0,0,0}, b3 = {0,0,0,0}, b4 = {0,0,0,0};

        // 13 iterations; slices 0..11 (zi = z0-2+k); ONE barrier each.
        for (int k = 0; k <= ZS + 4; ++k) {
            // Prefetch slice k+1 records (global; survives BAR_LDS).
            unsigned int q0 = 0, q1 = 0, q2 = 0;
            if (k + 1 <= ZS + 3) {
                int Mn = cm[k + 1][0] + cm[k + 1][1] + cm[k + 1][2];
                if (tid < Mn)       q0 = load_rec(k + 1, tid);
                if (tid + 256 < Mn) q1 = load_rec(k + 1, tid + 256);
                if (tid + 512 < Mn) q2 = load_rec(k + 1, tid + 512);
            }
            // Scatter slice k into buf k%3 (zeroed at iteration k-1).
            if (k <= ZS + 3) {
                const int M = cm[k][0] + cm[k][1] + cm[k][2];
                auto scat = [&](unsigned int r) {
                    int x  = r & 255;
                    int y  = (r >> 8) & 255;
                    int ry = y - y0 + 2;
                    if ((unsigned)ry < (unsigned)WROWS) {
                        float f = __half2float(__ushort_as_half((unsigned short)(r >> 16)));
                        #pragma unroll
                        for (int dx = -2; dx <= 2; ++dx) {
                            int cc = x + dx;
                            if ((unsigned)cc < 256u)
                                atomicAdd(&Xp[k % 3][ry][cc], f);
                        }
                    }
                };
                if (tid < M)       scat(p0);
                if (tid + 256 < M) scat(p1);
                if (tid + 512 < M) scat(p2);
            }
            // Zero buf (k+1)%3 for next slice (its data was read at iteration k-1).
            if (k + 1 <= ZS + 3)
                for (int idx = tid; idx < WROWS * 64; idx += NTHR)
                    ((float4*)Xp[(k + 1) % 3])[idx] = make_float4(0.f, 0.f, 0.f, 0.f);
            // y-pass of slice j=k-1 from buf (k-1)%3 (scattered last iteration).
            if (k >= 1) {
                const int pb = (k - 1) % 3;
                float4 r0 = *(const float4*)&Xp[pb][yy2 + 0][xq];
                float4 r1 = *(const float4*)&Xp[pb][yy2 + 1][xq];
                float4 r2 = *(const float4*)&Xp[pb][yy2 + 2][xq];
                float4 r3 = *(const float4*)&Xp[pb][yy2 + 3][xq];
                float4 r4 = *(const float4*)&Xp[pb][yy2 + 4][xq];
                float4 r5 = *(const float4*)&Xp[pb][yy2 + 5][xq];
                float4 sm, v0, v1;
                sm.x = r1.x + r2.x + r3.x + r4.x;  sm.y = r1.y + r2.y + r3.y + r4.y;
                sm.z = r1.z + r2.z + r3.z + r4.z;  sm.w = r1.w + r2.w + r3.w + r4.w;
                v0.x = sm.x + r0.x; v0.y = sm.y + r0.y; v0.z = sm.z + r0.z; v0.w = sm.w + r0.w;
                v1.x = sm.x + r5.x; v1.y = sm.y + r5.y; v1.z = sm.z + r5.z; v1.w = sm.w + r5.w;
                a0 = a1; a1 = a2; a2 = a3; a3 = a4; a4 = v0;
                b0 = b1; b1 = b2; b2 = b3; b3 = b4; b4 = v1;
                int j = k - 1;
                if (j >= 4) {
                    int zo = z0 + j - 4;           // z0 .. z0+7
                    floatx4 s0, s1;
                    s0.x = a0.x + a1.x + a2.x + a3.x + a4.x;
                    s0.y = a0.y + a1.y + a2.y + a3.y + a4.y;
                    s0.z = a0.z + a1.z + a2.z + a3.z + a4.z;
                    s0.w = a0.w + a1.w + a2.w + a3.w + a4.w;
                    s1.x = b0.x + b1.x + b2.x + b3.x + b4.x;
                    s1.y = b0.y + b1.y + b2.y + b3.y + b4.y;
                    s1.z = b0.z + b1.z + b2.z + b3.z + b4.z;
                    s1.w = b0.w + b1.w + b2.w + b3.w + b4.w;
                    float* base = out + (size_t)zo * (GRIDN * GRIDN);
                    __builtin_nontemporal_store(s0, (floatx4*)(base + (size_t)(y0 + yy2) * GRIDN + xq));
                    __builtin_nontemporal_store(s1, (floatx4*)(base + (size_t)(y0 + yy2 + 1) * GRIDN + xq));
                }
            }
            BAR_LDS();
            p0 = q0; p1 = q1; p2 = q2;
        }
    }
}

// ---------------------------------------------------------------------------
// Fallback if ws too small: zero out, then 125-way atomic expansion.
// ---------------------------------------------------------------------------
__global__ __launch_bounds__(256) void k_zero4(floatx4* __restrict__ p, int n4) {
    int stride = gridDim.x * blockDim.x;
    floatx4 z = {0.f, 0.f, 0.f, 0.f};
    for (int i = blockIdx.x * blockDim.x + threadIdx.x; i < n4; i += stride)
        __builtin_nontemporal_store(z, &p[i]);
}

__global__ void k_scatter125(const float* __restrict__ feats,
                             const int* __restrict__ coords,
                             float* __restrict__ out, int n) {
    int i = blockIdx.x * blockDim.x + threadIdx.x;
    if (i >= n) return;
    int d = coords[3 * i + 0];
    int h = coords[3 * i + 1];
    int w = coords[3 * i + 2];
    float f = feats[i];
    int d0 = max(d - 2, 0), d1 = min(d + 2, GRIDN - 1);
    int h0 = max(h - 2, 0), h1 = min(h + 2, GRIDN - 1);
    int w0 = max(w - 2, 0), w1 = min(w + 2, GRIDN - 1);
    for (int dd = d0; dd <= d1; ++dd)
        for (int hh = h0; hh <= h1; ++hh)
            for (int ww = w0; ww <= w1; ++ww)
                atomicAdd(&out[(dd * GRIDN + hh) * GRIDN + ww], f);
}

extern "C" void kernel_launch(void* const* d_in, const int* in_sizes, int n_in,
                              void* d_out, int out_size, void* d_ws, size_t ws_size,
                              hipStream_t stream) {
    const float* feats  = (const float*)d_in[0];
    const int*   coords = (const int*)d_in[1];
    float*       out    = (float*)d_out;
    int n = in_sizes[0];

    const size_t cnt_bytes = (size_t)NBKT * CSTR * sizeof(int);          // 1 MiB
    const size_t rec_bytes = (size_t)NBKT * BCAP * sizeof(unsigned int); // 8 MiB

    if (ws_size >= cnt_bytes + rec_bytes) {
        int*          cnt = (int*)d_ws;
        unsigned int* rec = (unsigned int*)((char*)d_ws + cnt_bytes);
        void* args[] = { (void*)&feats, (void*)&coords, (void*)&cnt,
                         (void*)&rec, (void*)&out, (void*)&n };
        hipLaunchCooperativeKernel((const void*)k_all, dim3(NBLK), dim3(NTHR),
                                   args, 0, stream);
    } else {
        k_zero4<<<4096, 256, 0, stream>>>((floatx4*)out, NVOX / 4);
        k_scatter125<<<(n + 255) / 256, 256, 0, stream>>>(feats, coords, out, n);
    }
}

// Round 14
// 75.778 us; speedup vs baseline: 3.0173x; 3.0173x over previous
//
#include <hip/hip_runtime.h>
#include <hip/hip_fp16.h>

#define GRIDN 256
#define NVOX (GRIDN * GRIDN * GRIDN)   // 64 MiB fp32
#define NYT  32                        // y-tiles of 8 rows
#define NBKT (GRIDN * NYT)             // 8192 base buckets: key = z*32 + (y>>3)
#define NSUB 8                         // sub-buckets by (bid & 7)  (~1 XCD each)
#define SBCAP 32                       // per-(key,sub) capacity (lambda 7.6)

#define TYF   8
#define WROWS 12                       // y0-2 .. y0+9
#define ZS    8
#define NTHR  256

typedef float floatx4 __attribute__((ext_vector_type(4)));

// LDS-only barrier: don't drain vmcnt (record prefetch + NT output stores
// stay in flight across it).
#define BAR_LDS()                                              \
    do {                                                       \
        asm volatile("s_waitcnt lgkmcnt(0)" ::: "memory");     \
        __builtin_amdgcn_sched_barrier(0);                     \
        __builtin_amdgcn_s_barrier();                          \
        __builtin_amdgcn_sched_barrier(0);                     \
    } while (0)

// ---------------------------------------------------------------------------
// Bin: sub-bucket (key, s=bid&7). cnt laid out [s][key] -> each 64B line
// holds 16 same-s keys => written by one XCD only (kills line ping-pong).
// rec run per (key,s) = 32 x 4B = 128B, same-XCD too. record={x:8,y:8,f16:16}.
// ---------------------------------------------------------------------------
__global__ __launch_bounds__(NTHR) void k_bin(const float* __restrict__ feats,
                                              const int* __restrict__ coords,
                                              int* __restrict__ cnt,
                                              unsigned int* __restrict__ rec, int n) {
    int i = blockIdx.x * NTHR + threadIdx.x;
    if (i >= n) return;
    int d = coords[3 * i + 0];
    int h = coords[3 * i + 1];
    int w = coords[3 * i + 2];
    int s   = blockIdx.x & (NSUB - 1);
    int key = s * NBKT + d * NYT + (h >> 3);
    int slot = atomicAdd(&cnt[key], 1);
    if (slot < SBCAP) {
        unsigned int r = (unsigned int)w | ((unsigned int)h << 8)
                       | ((unsigned int)__half_as_ushort(__float2half(feats[i])) << 16);
        rec[((size_t)key << 5) + slot] = r;
    }
}

// ---------------------------------------------------------------------------
// Sparse fused 5x5x5 box conv, v5: 3-buffer rotation, ONE barrier per slice,
// statically-slotted records (24 segments x 32 slots = 768 = 3 regs x 256 thr).
// Block = 256 thr, tile 256(x) x 8(y) x 8(z out). Grid 1024, XCD-swizzled.
// Iter k (0..12): prefetch slice k+1; scatter slice k -> buf k%3;
// zero buf (k+1)%3; y-pass slice k-1 from buf (k-1)%3; ring+store; BAR.
// Hazards all separated by exactly one barrier (3-buf rotation).
// ---------------------------------------------------------------------------
__global__ __launch_bounds__(NTHR) void k_fused_sparse(const int* __restrict__ cnt,
                                                       const unsigned int* __restrict__ rec,
                                                       float* __restrict__ out) {
    __shared__ float Xp[3][WROWS][256];
    __shared__ int   cms[ZS + 4][24];    // count per (slice k, seg q=(t*8+s))
    __shared__ int   rbs[ZS + 4][24];    // rec base index per (k, q)

    const int tid = threadIdx.x;
    int wg  = blockIdx.x;
    int swz = (wg & 7) * 128 + (wg >> 3);        // XCD-chunked, bijective (1024%8==0)
    const int y0 = (swz & 31) * TYF;
    const int z0 = (swz >> 5) * ZS;

    const int xq  = (tid & 63) * 4;    // float4 col in the row
    const int yy2 = (tid >> 6) * 2;    // 2 output rows per thread
    const int yt0 = y0 >> 3;

    // Prologue: load 12x24 sub-bucket counts/bases; zero all 3 buffers.
    for (int idx = tid; idx < (ZS + 4) * 24; idx += NTHR) {
        int k = idx / 24, q = idx - 24 * k;
        int t = q >> 3, s = q & 7;
        int zi = z0 - 2 + k;
        int yt = yt0 - 1 + t;
        int m = 0, b = 0;
        if ((unsigned)zi < (unsigned)GRIDN && (unsigned)yt < (unsigned)NYT) {
            int key = s * NBKT + zi * NYT + yt;
            m = min(cnt[key], SBCAP);
            b = key << 5;
        }
        cms[k][q] = m;
        rbs[k][q] = b;
    }
    for (int idx = tid; idx < 3 * WROWS * 64; idx += NTHR)
        ((float4*)Xp)[idx] = make_float4(0.f, 0.f, 0.f, 0.f);
    BAR_LDS();

    // Static slots: reg r, thread tid -> L = r*256+tid, seg q = L>>5, slot = L&31.
    const int q0s = (0 * 256 + tid) >> 5, sl0 = tid & 31;
    const int q1s = (1 * 256 + tid) >> 5, sl1 = tid & 31;
    const int q2s = (2 * 256 + tid) >> 5, sl2 = tid & 31;

    auto fetch = [&](int k, unsigned int& r0, unsigned int& r1, unsigned int& r2) {
        r0 = (sl0 < cms[k][q0s]) ? rec[rbs[k][q0s] + sl0] : 0u;
        r1 = (sl1 < cms[k][q1s]) ? rec[rbs[k][q1s] + sl1] : 0u;
        r2 = (sl2 < cms[k][q2s]) ? rec[rbs[k][q2s] + sl2] : 0u;
    };

    // Prefetch slice 0.  (record value 0 decodes to f=0 -> harmless, but we
    // gate scatter identically to fetch so 0-records are never applied.)
    unsigned int p0, p1, p2;
    fetch(0, p0, p1, p2);

    float4 a0 = {0,0,0,0}, a1 = {0,0,0,0}, a2 = {0,0,0,0}, a3 = {0,0,0,0}, a4 = {0,0,0,0};
    float4 b0 = {0,0,0,0}, b1 = {0,0,0,0}, b2 = {0,0,0,0}, b3 = {0,0,0,0}, b4 = {0,0,0,0};

    for (int k = 0; k <= ZS + 4; ++k) {
        // Prefetch slice k+1 (in flight across the barrier).
        unsigned int n0 = 0, n1 = 0, n2 = 0;
        if (k + 1 <= ZS + 3) fetch(k + 1, n0, n1, n2);

        // Scatter slice k into buf k%3.
        if (k <= ZS + 3) {
            float (*buf)[256] = Xp[k % 3];
            auto scat = [&](unsigned int r, int ok) {
                if (!ok) return;
                int x  = r & 255;
                int y  = (r >> 8) & 255;
                int ry = y - y0 + 2;
                if ((unsigned)ry < (unsigned)WROWS) {
                    float f = __half2float(__ushort_as_half((unsigned short)(r >> 16)));
                    #pragma unroll
                    for (int dx = -2; dx <= 2; ++dx) {
                        int cc = x + dx;
                        if ((unsigned)cc < 256u)
                            atomicAdd(&buf[ry][cc], f);
                    }
                }
            };
            scat(p0, sl0 < cms[k][q0s]);
            scat(p1, sl1 < cms[k][q1s]);
            scat(p2, sl2 < cms[k][q2s]);
        }
        // Zero buf (k+1)%3 (y-passed at iter k-1; one barrier since).
        if (k + 1 <= ZS + 3) {
            float4* zb = (float4*)Xp[(k + 1) % 3];
            for (int idx = tid; idx < WROWS * 64; idx += NTHR)
                zb[idx] = make_float4(0.f, 0.f, 0.f, 0.f);
        }
        // y-pass slice k-1 from buf (k-1)%3 (scattered at k-1; barrier since).
        if (k >= 1) {
            float (*pb)[256] = Xp[(k - 1) % 3];
            float4 r0 = *(const float4*)&pb[yy2 + 0][xq];
            float4 r1 = *(const float4*)&pb[yy2 + 1][xq];
            float4 r2 = *(const float4*)&pb[yy2 + 2][xq];
            float4 r3 = *(const float4*)&pb[yy2 + 3][xq];
            float4 r4 = *(const float4*)&pb[yy2 + 4][xq];
            float4 r5 = *(const float4*)&pb[yy2 + 5][xq];
            float4 sm, v0, v1;
            sm.x = r1.x + r2.x + r3.x + r4.x;  sm.y = r1.y + r2.y + r3.y + r4.y;
            sm.z = r1.z + r2.z + r3.z + r4.z;  sm.w = r1.w + r2.w + r3.w + r4.w;
            v0.x = sm.x + r0.x; v0.y = sm.y + r0.y; v0.z = sm.z + r0.z; v0.w = sm.w + r0.w;
            v1.x = sm.x + r5.x; v1.y = sm.y + r5.y; v1.z = sm.z + r5.z; v1.w = sm.w + r5.w;
            a0 = a1; a1 = a2; a2 = a3; a3 = a4; a4 = v0;
            b0 = b1; b1 = b2; b2 = b3; b3 = b4; b4 = v1;
            int j = k - 1;
            if (j >= 4) {
                int zo = z0 + j - 4;
                floatx4 s0, s1;
                s0.x = a0.x + a1.x + a2.x + a3.x + a4.x;
                s0.y = a0.y + a1.y + a2.y + a3.y + a4.y;
                s0.z = a0.z + a1.z + a2.z + a3.z + a4.z;
                s0.w = a0.w + a1.w + a2.w + a3.w + a4.w;
                s1.x = b0.x + b1.x + b2.x + b3.x + b4.x;
                s1.y = b0.y + b1.y + b2.y + b3.y + b4.y;
                s1.z = b0.z + b1.z + b2.z + b3.z + b4.z;
                s1.w = b0.w + b1.w + b2.w + b3.w + b4.w;
                float* base = out + (size_t)zo * (GRIDN * GRIDN);
                __builtin_nontemporal_store(s0, (floatx4*)(base + (size_t)(y0 + yy2) * GRIDN + xq));
                __builtin_nontemporal_store(s1, (floatx4*)(base + (size_t)(y0 + yy2 + 1) * GRIDN + xq));
            }
        }
        BAR_LDS();
        p0 = n0; p1 = n1; p2 = n2;
    }
}

// ---------------------------------------------------------------------------
// Fallback if ws too small: zero out, then 125-way atomic expansion.
// ---------------------------------------------------------------------------
__global__ __launch_bounds__(256) void k_zero4(floatx4* __restrict__ p, int n4) {
    int stride = gridDim.x * blockDim.x;
    floatx4 z = {0.f, 0.f, 0.f, 0.f};
    for (int i = blockIdx.x * blockDim.x + threadIdx.x; i < n4; i += stride)
        __builtin_nontemporal_store(z, &p[i]);
}

__global__ void k_scatter125(const float* __restrict__ feats,
                             const int* __restrict__ coords,
                             float* __restrict__ out, int n) {
    int i = blockIdx.x * blockDim.x + threadIdx.x;
    if (i >= n) return;
    int d = coords[3 * i + 0];
    int h = coords[3 * i + 1];
    int w = coords[3 * i + 2];
    float f = feats[i];
    int d0 = max(d - 2, 0), d1 = min(d + 2, GRIDN - 1);
    int h0 = max(h - 2, 0), h1 = min(h + 2, GRIDN - 1);
    int w0 = max(w - 2, 0), w1 = min(w + 2, GRIDN - 1);
    for (int dd = d0; dd <= d1; ++dd)
        for (int hh = h0; hh <= h1; ++hh)
            for (int ww = w0; ww <= w1; ++ww)
                atomicAdd(&out[(dd * GRIDN + hh) * GRIDN + ww], f);
}

extern "C" void kernel_launch(void* const* d_in, const int* in_sizes, int n_in,
                              void* d_out, int out_size, void* d_ws, size_t ws_size,
                              hipStream_t stream) {
    const float* feats  = (const float*)d_in[0];
    const int*   coords = (const int*)d_in[1];
    float*       out    = (float*)d_out;
    int n = in_sizes[0];

    const size_t cnt_bytes = (size_t)NSUB * NBKT * sizeof(int);                  // 256 KiB
    const size_t rec_bytes = (size_t)NSUB * NBKT * SBCAP * sizeof(unsigned int); // 8 MiB

    if (ws_size >= cnt_bytes + rec_bytes) {
        int*          cnt = (int*)d_ws;
        unsigned int* rec = (unsigned int*)((char*)d_ws + cnt_bytes);
        hipMemsetAsync(cnt, 0, cnt_bytes, stream);
        k_bin<<<(n + NTHR - 1) / NTHR, NTHR, 0, stream>>>(feats, coords, cnt, rec, n);
        k_fused_sparse<<<1024, NTHR, 0, stream>>>(cnt, rec, out);
    } else {
        k_zero4<<<4096, 256, 0, stream>>>((floatx4*)out, NVOX / 4);
        k_scatter125<<<(n + 255) / 256, 256, 0, stream>>>(feats, coords, out, n);
    }
}